// Round 1
// baseline (10864.506 us; speedup 1.0000x reference)
//
#include <hip/hip_runtime.h>
#include <cstdint>
#include <cstddef>

// Problem constants
#define B_  4096
#define H_  300
#define T_  43
#define NC_ 80
#define HP  320      // padded hidden/input dim (300 -> 320)
#define ND  1280     // padded 4H per direction
#define NDD 2560     // both directions
#define KC  640      // concatenated K: [x_t (320) ; h_prev (320)]
#define TR  304      // hs per-t row length in f16 (300 + 4 zero pad, 16B aligned)
#define SB2 (T_ * TR) // hs per-(d,b) stride in f16 = 13072

typedef _Float16 f16;
typedef _Float16 half8 __attribute__((ext_vector_type(8)));
typedef _Float16 half4 __attribute__((ext_vector_type(4)));
typedef float    f32x4 __attribute__((ext_vector_type(4)));

__device__ __forceinline__ void gl_lds16(const void* g, void* l) {
  __builtin_amdgcn_global_load_lds(
      (const __attribute__((address_space(1))) void*)g,
      (__attribute__((address_space(3))) void*)l, 16, 0, 0);
}
__device__ __forceinline__ float sigmoid_(float x) {
  return 1.f / (1.f + __expf(-x));
}
__device__ __forceinline__ float tanh_fast(float x) {
  x = fminf(fmaxf(x, -15.f), 15.f);
  float e = __expf(2.f * x);
  return (e - 1.f) / (e + 1.f);
}

// ---------------------------------------------------------------------------
// Weight packing, concatenated-K layout. Row index = d*1280 + 4*jh + g
// (gate-interleaved, order i,f,g,o). Wcat[2560][640]: cols 0..319 = Wih row
// (k < 300 real), cols 320..639 = Whh row. bias[2560] = b_ih + b_hh.
// ---------------------------------------------------------------------------
__global__ void prep_weights(const float* __restrict__ w_ih,
                             const float* __restrict__ w_hh,
                             const float* __restrict__ b_ih,
                             const float* __restrict__ b_hh,
                             f16* __restrict__ Wcat, float* __restrict__ bias) {
  int idx = blockIdx.x * 256 + threadIdx.x;
  const int total = NDD * KC;
  if (idx < total) {
    int row = idx / KC, k = idx % KC;
    int d = row / ND, n = row % ND;
    int jh = n >> 2, g = n & 3;
    int which = (k >= HP);           // 0 = Wih part, 1 = Whh part
    int kk = which ? (k - HP) : k;
    float v = 0.f;
    if (jh < H_ && kk < H_) {
      const float* W = which ? w_hh : w_ih;
      v = W[((size_t)d * 4 * H_ + g * H_ + jh) * H_ + kk];
    }
    Wcat[(size_t)row * KC + k] = (f16)v;
  }
  if (idx < NDD) {
    int d = idx / ND, n = idx % ND;
    int jh = n >> 2, g = n & 3;
    float v = 0.f;
    if (jh < H_)
      v = b_ih[d * 4 * H_ + g * H_ + jh] + b_hh[d * 4 * H_ + g * H_ + jh];
    bias[idx] = v;
  }
}

// ---------------------------------------------------------------------------
// x [B,H,T] fp32 -> xT[t*B+b][k] f16, k padded to 320 with zeros.
// ---------------------------------------------------------------------------
__global__ void prep_xT(const float* __restrict__ x, f16* __restrict__ xT) {
  __shared__ float tile[64][44];
  int b = blockIdx.x, ch = blockIdx.y;
  int h0 = ch * 64;
  for (int idx = threadIdx.x; idx < 64 * T_; idx += 256) {
    int hh = idx / T_, t = idx % T_;
    float v = 0.f;
    if (h0 + hh < H_) v = x[((size_t)b * H_ + h0 + hh) * T_ + t];
    tile[hh][t] = v;
  }
  __syncthreads();
  for (int idx = threadIdx.x; idx < 64 * T_; idx += 256) {
    int t = idx / 64, hh = idx % 64;
    xT[((size_t)t * B_ + b) * HP + h0 + hh] = (f16)tile[hh][t];
  }
}

// ---------------------------------------------------------------------------
// Persistent bidirectional-LSTM kernel: ALL 43 timesteps in one launch.
//   z = Wcat @ [x_t ; h_prev]  (K = 640), gates in acc regs (4 per lane),
//   c carried in registers across the whole sequence (creg[4][4]).
// Cross-block dependency is only among the 10 wt-blocks of a (bt,d) group:
// synced via a per-group monotonic counter (device-scope atomics + fences).
// grid (10 jh-tiles, 32 b-tiles, 2 dirs) = 640 blocks, 256 thr.
// __launch_bounds__(256,3) guarantees 3 blocks/CU -> 768 >= 640 co-resident.
// ---------------------------------------------------------------------------
__global__ __launch_bounds__(256, 3) void lstm_all(
    const f16* __restrict__ xT,     // [T][B][320]
    f16* __restrict__ h0g,          // ping  [2][B][320]
    f16* __restrict__ h1g,          // pong  [2][B][320]
    const f16* __restrict__ Wcat,   // [2560][640]
    const float* __restrict__ bias, // [2560]
    f16* __restrict__ hs,           // [2][B][43][304]
    unsigned int* __restrict__ syncv) {
  __shared__ __attribute__((aligned(16))) char smem[16384];
  f16* As = (f16*)smem;
  f16* Bs = (f16*)(smem + 8192);
  f16* tile = (f16*)smem;  // 32 x 136 f16 = 8704 B, reused after GEMM

  const int tid = threadIdx.x;
  const int wave = tid >> 6, lane = tid & 63;
  const int wt = blockIdx.x, bt = blockIdx.y, d = blockIdx.z;
  const int lrow4 = lane >> 2, col8 = (lane & 3) << 3;
  const int wm = wave & 1, wn = wave >> 1;
  const int lr = lane & 15, lq = lane >> 4;
  const int kq = lq << 3;

  const f16* Wb = Wcat + ((size_t)d * ND + wt * 128) * KC;
  unsigned int* ctr = syncv + (((d << 5) | bt) << 4);  // 64B-padded counters

  float creg[4][4];
#pragma unroll
  for (int i = 0; i < 4; i++)
#pragma unroll
    for (int j = 0; j < 4; j++) creg[i][j] = 0.f;

  for (int t = 0; t < T_; ++t) {
    const f16* hp = (t & 1) ? h1g : h0g;
    f16* hn = (t & 1) ? h0g : h1g;
    const f16* hb = hp + ((size_t)d * B_ + bt * 128) * HP;
    const f16* xb = xT + ((size_t)t * B_ + bt * 128) * HP;

    f32x4 acc[4][4];
#pragma unroll
    for (int i = 0; i < 4; i++)
#pragma unroll
      for (int j = 0; j < 4; j++) acc[i][j] = (f32x4){0.f, 0.f, 0.f, 0.f};

    for (int kt = 0; kt < KC / 32; ++kt) {
      __syncthreads();
      const f16* Bsrc = (kt < 10) ? (xb + kt * 32) : (hb + (kt - 10) * 32);
#pragma unroll
      for (int i = 0; i < 2; i++) {
        int r0 = wave * 32 + i * 16;
        gl_lds16(Wb + (size_t)(r0 + lrow4) * KC + kt * 32 + col8, &As[r0 * 32]);
        gl_lds16(Bsrc + (size_t)(r0 + lrow4) * HP + col8, &Bs[r0 * 32]);
      }
      __syncthreads();
      half8 af[4], bf[4];
#pragma unroll
      for (int i = 0; i < 4; i++) {
        af[i] = *(const half8*)&As[(wm * 64 + i * 16 + lr) * 32 + kq];
        bf[i] = *(const half8*)&Bs[(wn * 64 + i * 16 + lr) * 32 + kq];
      }
#pragma unroll
      for (int i = 0; i < 4; i++)
#pragma unroll
        for (int j = 0; j < 4; j++)
          acc[i][j] = __builtin_amdgcn_mfma_f32_16x16x32_f16(af[i], bf[j],
                                                             acc[i][j], 0, 0, 0);
    }

    __syncthreads();  // all LDS reads done before tile reuse

    // Gate epilogue -> stage hn into LDS tile [jh_local][b_local], stride 136.
#pragma unroll
    for (int i = 0; i < 4; i++) {
      const int jl = wm * 16 + i * 4 + lq;  // 0..31
      const int jh = wt * 32 + jl;
      float4 b4 = {0.f, 0.f, 0.f, 0.f};
      if (jh < H_) b4 = *(const float4*)&bias[d * ND + 4 * jh];
#pragma unroll
      for (int j = 0; j < 4; j++) {
        const int bl = wn * 64 + j * 16 + lr;  // 0..127
        f16 hnv = (f16)0.f;
        if (jh < H_) {
          float zi = acc[i][j][0] + b4.x;
          float zf = acc[i][j][1] + b4.y;
          float zg = acc[i][j][2] + b4.z;
          float zo = acc[i][j][3] + b4.w;
          float co = creg[i][j];
          float cn = sigmoid_(zf) * co + sigmoid_(zi) * tanh_fast(zg);
          creg[i][j] = cn;
          hnv = (f16)(sigmoid_(zo) * tanh_fast(cn));
        }
        tile[jl * 136 + bl] = hnv;
      }
    }
    __syncthreads();

    // Coalesced write-out: thread -> (b_local = tid>>1, 16-jh half = tid&1).
    {
      const int bl = tid >> 1, jhalf = tid & 1;
      const int b = bt * 128 + bl;
      f16 vals[16];
#pragma unroll
      for (int jj = 0; jj < 16; jj++)
        vals[jj] = tile[(jhalf * 16 + jj) * 136 + bl];
      half8 v0, v1;
#pragma unroll
      for (int r = 0; r < 8; r++) { v0[r] = vals[r]; v1[r] = vals[8 + r]; }

      const int jh0 = wt * 32 + jhalf * 16;
      f16* hdst = hn + ((size_t)d * B_ + b) * HP + jh0;
      *(half8*)hdst = v0;
      *(half8*)(hdst + 8) = v1;

      if (jh0 < H_) {  // wt==9,jhalf==1 (jh 304..319) has no hs slot
        f16* sdst = hs + ((size_t)d * B_ + b) * SB2 + t * TR + jh0;
        *(half8*)sdst = v0;      // wt==9: jh 288..295 valid
        *(half8*)(sdst + 8) = v1;  // wt==9: 296..299 valid + 4 zeros -> row pad
      }
    }

    // Group sync: the 10 wt-blocks of (bt,d) must all finish step t before
    // any proceeds (h ping-pong read/write hazard). Device-scope since blocks
    // may sit on different XCDs (non-coherent L2s).
    if (t + 1 < T_) {
      __threadfence();    // each wave: drain stores + L2 writeback (release)
      __syncthreads();
      if (tid == 0) {
        __hip_atomic_fetch_add(ctr, 1u, __ATOMIC_RELEASE,
                               __HIP_MEMORY_SCOPE_AGENT);
        const unsigned int tgt = 10u * (unsigned int)(t + 1);
        while (__hip_atomic_load(ctr, __ATOMIC_ACQUIRE,
                                 __HIP_MEMORY_SCOPE_AGENT) < tgt)
          __builtin_amdgcn_s_sleep(2);
      }
      __syncthreads();
      __threadfence();    // acquire side: invalidate stale L1/L2 lines
    }
  }
}

// ---------------------------------------------------------------------------
// attn1: alpha[b][t] = softmax_t( sum_h tanh(hs0+hs1) * conv_w[h] ).
// Pure stream over hs; half4 loads (rows are 304-wide, zero-padded).
// ---------------------------------------------------------------------------
__global__ __launch_bounds__(256) void attn1(const f16* __restrict__ hs,
                                             const float* __restrict__ conv_w,
                                             float* __restrict__ alpha_g) {
  __shared__ float cw[TR];
  __shared__ float red[48];
  const int b = blockIdx.x, tid = threadIdx.x;
  const int wave = tid >> 6, lane = tid & 63;
  for (int k = tid; k < TR; k += 256) cw[k] = (k < H_) ? conv_w[k] : 0.f;
  __syncthreads();

  const half4* s0 = (const half4*)(hs + (size_t)b * SB2);
  const half4* s1 = (const half4*)(hs + (size_t)(B_ + b) * SB2);
  for (int t = wave; t < T_; t += 4) {
    const int base = t * (TR / 4);
    float p = 0.f;
    {
      half4 a = s0[base + lane], cc = s1[base + lane];
#pragma unroll
      for (int r = 0; r < 4; r++)
        p += tanh_fast((float)a[r] + (float)cc[r]) * cw[lane * 4 + r];
    }
    if (lane < 12) {
      half4 a = s0[base + 64 + lane], cc = s1[base + 64 + lane];
#pragma unroll
      for (int r = 0; r < 4; r++)
        p += tanh_fast((float)a[r] + (float)cc[r]) * cw[256 + lane * 4 + r];
    }
#pragma unroll
    for (int o = 32; o; o >>= 1) p += __shfl_down(p, o);
    if (lane == 0) red[t] = p;
  }
  __syncthreads();
  if (tid < 64) {
    float a = (tid < T_) ? red[tid] : -1e30f;
    float mx = a;
#pragma unroll
    for (int o = 32; o; o >>= 1) mx = fmaxf(mx, __shfl_xor(mx, o));
    float e = (tid < T_) ? __expf(a - mx) : 0.f;
    float s = e;
#pragma unroll
    for (int o = 32; o; o >>= 1) s += __shfl_xor(s, o);
    if (tid < T_) alpha_g[(size_t)b * 44 + tid] = e / s;
  }
}

// ---------------------------------------------------------------------------
// attn2: r[b][h] = sum_t hsum*alpha; hstar = tanh(r); logits; softmax.
// Thread-per-h accumulation, coalesced streaming.
// ---------------------------------------------------------------------------
__global__ __launch_bounds__(256) void attn2(const f16* __restrict__ hs,
                                             const float* __restrict__ alpha_g,
                                             const float* __restrict__ fc_w,
                                             const float* __restrict__ fc_b,
                                             float* __restrict__ out) {
  __shared__ float al[T_];
  __shared__ float hstar[TR];
  __shared__ float lg[NC_];
  const int b = blockIdx.x, tid = threadIdx.x;
  if (tid < T_) al[tid] = alpha_g[(size_t)b * 44 + tid];
  __syncthreads();

  const f16* s0 = hs + (size_t)b * SB2;
  const f16* s1 = hs + (size_t)(B_ + b) * SB2;
  float r0 = 0.f, r1 = 0.f;
  for (int t = 0; t < T_; t++) {
    const float a = al[t];
    r0 += ((float)s0[t * TR + tid] + (float)s1[t * TR + tid]) * a;
    if (tid < 48)
      r1 += ((float)s0[t * TR + 256 + tid] + (float)s1[t * TR + 256 + tid]) * a;
  }
  hstar[tid] = tanh_fast(r0);
  if (tid < 48) hstar[256 + tid] = tanh_fast(r1);
  __syncthreads();

  const int wave = tid >> 6, lane = tid & 63;
  for (int cls = wave; cls < NC_; cls += 4) {
    float p = 0.f;
    for (int k = lane; k < H_; k += 64) p += hstar[k] * fc_w[(size_t)cls * H_ + k];
#pragma unroll
    for (int o = 32; o; o >>= 1) p += __shfl_down(p, o);
    if (lane == 0) lg[cls] = p + fc_b[cls];
  }
  __syncthreads();
  if (tid < 64) {
    float a0 = (tid < 40) ? lg[tid] : -1e30f;
    float a1 = (tid < 40) ? lg[tid + 40] : -1e30f;
    float mx = fmaxf(a0, a1);
#pragma unroll
    for (int o = 32; o; o >>= 1) mx = fmaxf(mx, __shfl_xor(mx, o));
    float e0 = (tid < 40) ? __expf(a0 - mx) : 0.f;
    float e1 = (tid < 40) ? __expf(a1 - mx) : 0.f;
    float s = e0 + e1;
#pragma unroll
    for (int o = 32; o; o >>= 1) s += __shfl_xor(s, o);
    if (tid < 40) {
      out[(size_t)b * NC_ + tid] = e0 / s;
      out[(size_t)b * NC_ + tid + 40] = e1 / s;
    }
  }
}

// ---------------------------------------------------------------------------
extern "C" void kernel_launch(void* const* d_in, const int* in_sizes, int n_in,
                              void* d_out, int out_size, void* d_ws, size_t ws_size,
                              hipStream_t stream) {
  const float* x      = (const float*)d_in[0];
  const float* w_ih   = (const float*)d_in[1];
  const float* w_hh   = (const float*)d_in[2];
  const float* b_ih   = (const float*)d_in[3];
  const float* b_hh   = (const float*)d_in[4];
  const float* conv_w = (const float*)d_in[5];
  const float* fc_w   = (const float*)d_in[6];
  const float* fc_b   = (const float*)d_in[7];
  float* out = (float*)d_out;

  // Workspace carve (~341 MB)
  char* p = (char*)d_ws;
  f16* Wcat = (f16*)p;  p += (size_t)NDD * KC * sizeof(f16);        // 3.3 MB
  float* bias = (float*)p; p += (size_t)NDD * sizeof(float);
  p = (char*)(((uintptr_t)p + 255) & ~(uintptr_t)255);
  f16* xT = (f16*)p;    p += (size_t)T_ * B_ * HP * sizeof(f16);    // 112.7 MB
  f16* h  = (f16*)p;    p += (size_t)2 * 2 * B_ * HP * sizeof(f16); // 10.5 MB
  f16* hs = (f16*)p;    p += (size_t)2 * B_ * SB2 * sizeof(f16);    // 214.2 MB
  float* alpha_g = (float*)p; p += (size_t)B_ * 44 * sizeof(float); // 0.72 MB
  unsigned int* syncv = (unsigned int*)p; p += 64 * 64;             // 4 KB

  hipMemsetAsync(h, 0, (size_t)2 * 2 * B_ * HP * sizeof(f16), stream);
  hipMemsetAsync(syncv, 0, 64 * 64, stream);

  prep_weights<<<(NDD * KC + 255) / 256, 256, 0, stream>>>(
      w_ih, w_hh, b_ih, b_hh, Wcat, bias);
  prep_xT<<<dim3(B_, 5), 256, 0, stream>>>(x, xT);

  const size_t hstride = (size_t)2 * B_ * HP;  // f16 units per ping-pong buf
  lstm_all<<<dim3(10, 32, 2), 256, 0, stream>>>(
      xT, h, h + hstride, Wcat, bias, hs, syncv);

  attn1<<<B_, 256, 0, stream>>>(hs, conv_w, alpha_g);
  attn2<<<B_, 256, 0, stream>>>(hs, alpha_g, fc_w, fc_b, out);
}

// Round 2
// 3583.151 us; speedup vs baseline: 3.0321x; 3.0321x over previous
//
#include <hip/hip_runtime.h>
#include <cstdint>
#include <cstddef>

// Problem constants
#define B_  4096
#define H_  300
#define T_  43
#define NC_ 80
#define HP  320      // padded hidden/input dim (300 -> 320)
#define ND  1280     // padded 4H per direction
#define NDD 2560     // both directions
#define KC  640      // concatenated K: [x_t (320) ; h_prev (320)]
#define TR  304      // hs per-t row length in f16 (300 + 4 zero pad, 16B aligned)
#define SB2 (T_ * TR) // hs per-(d,b) stride in f16 = 13072
#define BT  32       // batch tile per block
#define NBT (B_ / BT) // 128 batch tiles

// LDS layout (bytes). Rows padded to 328 f16 (656 B = 164 words, 164%32=4
// -> strided ds_read_b128 spreads over all bank groups).
#define HROW 328
#define XS_OFF   0
#define H0_OFF   (XS_OFF + BT * HROW * 2)     // 20992
#define H1_OFF   (H0_OFF + BT * HROW * 2)     // 41984
#define C_OFF    (H1_OFF + BT * HROW * 2)     // 62976  (c[320][33] f32)
#define BIAS_OFF (C_OFF + 320 * 33 * 4)       // 105216 (bias[1280] f32)
#define LDS_TOTAL (BIAS_OFF + 1280 * 4)       // 110336

typedef _Float16 f16;
typedef _Float16 half8 __attribute__((ext_vector_type(8)));
typedef _Float16 half4 __attribute__((ext_vector_type(4)));
typedef float    f32x4 __attribute__((ext_vector_type(4)));

__device__ __forceinline__ float sigmoid_(float x) {
  return 1.f / (1.f + __expf(-x));
}
__device__ __forceinline__ float tanh_fast(float x) {
  x = fminf(fmaxf(x, -15.f), 15.f);
  float e = __expf(2.f * x);
  return (e - 1.f) / (e + 1.f);
}

// ---------------------------------------------------------------------------
// Weight packing, concatenated-K layout. Row index = d*1280 + 4*jh + g
// (gate-interleaved, order i,f,g,o). Wcat[2560][640]: cols 0..319 = Wih row
// (k < 300 real), cols 320..639 = Whh row. bias[2560] = b_ih + b_hh.
// ---------------------------------------------------------------------------
__global__ void prep_weights(const float* __restrict__ w_ih,
                             const float* __restrict__ w_hh,
                             const float* __restrict__ b_ih,
                             const float* __restrict__ b_hh,
                             f16* __restrict__ Wcat, float* __restrict__ bias) {
  int idx = blockIdx.x * 256 + threadIdx.x;
  const int total = NDD * KC;
  if (idx < total) {
    int row = idx / KC, k = idx % KC;
    int d = row / ND, n = row % ND;
    int jh = n >> 2, g = n & 3;
    int which = (k >= HP);           // 0 = Wih part, 1 = Whh part
    int kk = which ? (k - HP) : k;
    float v = 0.f;
    if (jh < H_ && kk < H_) {
      const float* W = which ? w_hh : w_ih;
      v = W[((size_t)d * 4 * H_ + g * H_ + jh) * H_ + kk];
    }
    Wcat[(size_t)row * KC + k] = (f16)v;
  }
  if (idx < NDD) {
    int d = idx / ND, n = idx % ND;
    int jh = n >> 2, g = n & 3;
    float v = 0.f;
    if (jh < H_)
      v = b_ih[d * 4 * H_ + g * H_ + jh] + b_hh[d * 4 * H_ + g * H_ + jh];
    bias[idx] = v;
  }
}

// ---------------------------------------------------------------------------
// x [B,H,T] fp32 -> xT[t*B+b][k] f16, k padded to 320 with zeros.
// ---------------------------------------------------------------------------
__global__ void prep_xT(const float* __restrict__ x, f16* __restrict__ xT) {
  __shared__ float tile[64][44];
  int b = blockIdx.x, ch = blockIdx.y;
  int h0 = ch * 64;
  for (int idx = threadIdx.x; idx < 64 * T_; idx += 256) {
    int hh = idx / T_, t = idx % T_;
    float v = 0.f;
    if (h0 + hh < H_) v = x[((size_t)b * H_ + h0 + hh) * T_ + t];
    tile[hh][t] = v;
  }
  __syncthreads();
  for (int idx = threadIdx.x; idx < 64 * T_; idx += 256) {
    int t = idx / 64, hh = idx % 64;
    xT[((size_t)t * B_ + b) * HP + h0 + hh] = (f16)tile[hh][t];
  }
}

// ---------------------------------------------------------------------------
// Batch-sliced persistent LSTM: one block owns (direction d, 32 batch rows)
// for ALL 43 timesteps. No inter-block dependency (LSTM recurrence is
// independent per batch element). h ping-pongs in LDS, c lives in LDS —
// zero global traffic for state. Weights stream L2 -> VGPR directly
// (no LDS staging, no barriers in the K-loop).
//   z[n=4jh+g][b] = Wcat[d] @ [x_t ; h_prev]   (K = 640)
// Per wave: 64 gate-rows per M-chunk; 5 M-chunks cover 1280 rows.
// grid (128 batch-tiles, 2 dirs) = 256 blocks = 1 per CU. 256 thr.
// ---------------------------------------------------------------------------
__global__ __launch_bounds__(256, 1) void lstm_all(
    const f16* __restrict__ xT,     // [T][B][320]
    const f16* __restrict__ Wcat,   // [2560][640]
    const float* __restrict__ bias, // [2560]
    f16* __restrict__ hs) {         // [2][B][43][304]
  extern __shared__ __attribute__((aligned(16))) char smem[];
  f16* xs = (f16*)(smem + XS_OFF);
  f16* h0s = (f16*)(smem + H0_OFF);
  f16* h1s = (f16*)(smem + H1_OFF);
  float* cls = (float*)(smem + C_OFF);
  float* bl = (float*)(smem + BIAS_OFF);

  const int tid = threadIdx.x;
  const int wave = tid >> 6, lane = tid & 63;
  const int lr = lane & 15, lq = lane >> 4;
  const int bt = blockIdx.x, d = blockIdx.y;

  // ---- init: bias -> LDS, zero c, zero h0 ----
  for (int i = tid; i < 1280; i += 256) bl[i] = bias[d * ND + i];
  for (int i = tid; i < 320 * 33; i += 256) cls[i] = 0.f;
  for (int i = tid; i < BT * HROW; i += 256) h0s[i] = (f16)0.f;

  // x staging map: 1280 16B-chunks = 5 per thread. chunk -> (b row, col chunk)
  size_t goff[5];
  int doff[5];
#pragma unroll
  for (int p = 0; p < 5; ++p) {
    int idx = p * 256 + tid;
    int bb = idx / 40, cc = idx % 40;     // 40 chunks of 16B per 320-f16 row
    goff[p] = ((size_t)(bt * BT + bb)) * HP + cc * 8;
    doff[p] = bb * HROW + cc * 8;
  }

  // stage x_0
  {
    half8 x0[5];
#pragma unroll
    for (int p = 0; p < 5; ++p) x0[p] = *(const half8*)(xT + goff[p]);
#pragma unroll
    for (int p = 0; p < 5; ++p) *(half8*)(xs + doff[p]) = x0[p];
  }
  __syncthreads();

  for (int t = 0; t < T_; ++t) {
    const f16* hcur = (t & 1) ? h1s : h0s;
    f16* hnxt = (t & 1) ? h0s : h1s;

    // prefetch x_{t+1} to regs (latency hides under GEMM)
    half8 xn[5];
    if (t + 1 < T_) {
      const f16* xsrc = xT + (size_t)(t + 1) * B_ * HP;
#pragma unroll
      for (int p = 0; p < 5; ++p) xn[p] = *(const half8*)(xsrc + goff[p]);
    }

    // ---- GEMM z = Wcat @ [x_t ; h_prev], 5 M-chunks of 256 rows ----
    for (int m = 0; m < 5; ++m) {
      const f16* wr =
          Wcat + ((size_t)d * ND + m * 256 + wave * 64 + lr) * KC + lq * 8;
      f32x4 acc[4][2];
#pragma unroll
      for (int i = 0; i < 4; i++)
#pragma unroll
        for (int j = 0; j < 2; j++) acc[i][j] = (f32x4){0.f, 0.f, 0.f, 0.f};

#pragma unroll
      for (int kt = 0; kt < 20; ++kt) {
        const f16* bslab = (kt < 10) ? xs : hcur;
        const int ko = (kt < 10) ? kt * 32 : (kt - 10) * 32;
        half8 af[4], bf[2];
#pragma unroll
        for (int i = 0; i < 4; i++)
          af[i] = *(const half8*)(wr + (size_t)i * 16 * KC + kt * 32);
#pragma unroll
        for (int j = 0; j < 2; j++)
          bf[j] = *(const half8*)(bslab + (j * 16 + lr) * HROW + ko + lq * 8);
#pragma unroll
        for (int i = 0; i < 4; i++)
#pragma unroll
          for (int j = 0; j < 2; j++)
            acc[i][j] = __builtin_amdgcn_mfma_f32_16x16x32_f16(
                af[i], bf[j], acc[i][j], 0, 0, 0);
      }

      // ---- gate epilogue for this M-chunk: c (LDS), h_new -> hnxt ----
#pragma unroll
      for (int i = 0; i < 4; i++) {
        const int jh = m * 64 + wave * 16 + i * 4 + lq;  // 0..319
        const float4 b4 = *(const float4*)&bl[4 * jh];
#pragma unroll
        for (int j = 0; j < 2; j++) {
          const int b = j * 16 + lr;  // 0..31
          float* cp = &cls[jh * 33 + b];
          const float co = *cp;
          const float zi = acc[i][j][0] + b4.x;
          const float zf = acc[i][j][1] + b4.y;
          const float zg = acc[i][j][2] + b4.z;
          const float zo = acc[i][j][3] + b4.w;
          const float cn = sigmoid_(zf) * co + sigmoid_(zi) * tanh_fast(zg);
          *cp = cn;
          hnxt[b * HROW + jh] = (f16)(sigmoid_(zo) * tanh_fast(cn));
        }
      }
    }
    __syncthreads();  // hnxt complete

    // ---- hs write-out: rows [b][304] contiguous from hnxt row b ----
    {
      const int b = tid >> 3, sub = tid & 7;
      const f16* src = hnxt + b * HROW;
      f16* dst = hs + ((size_t)d * B_ + bt * BT + b) * SB2 + t * TR;
      const int c0 = sub * 5;
      const int c1 = (c0 + 5 < 38) ? c0 + 5 : 38;  // 38 half8 chunks = 304 f16
      for (int ch = c0; ch < c1; ++ch)
        *(half8*)(dst + ch * 8) = *(const half8*)(src + ch * 8);
    }
    // ---- commit prefetched x_{t+1} ----
    if (t + 1 < T_) {
#pragma unroll
      for (int p = 0; p < 5; ++p) *(half8*)(xs + doff[p]) = xn[p];
    }
    __syncthreads();
  }
}

// ---------------------------------------------------------------------------
// attn1: alpha[b][t] = softmax_t( sum_h tanh(hs0+hs1) * conv_w[h] ).
// Pure stream over hs; half4 loads (rows are 304-wide, zero-padded).
// ---------------------------------------------------------------------------
__global__ __launch_bounds__(256) void attn1(const f16* __restrict__ hs,
                                             const float* __restrict__ conv_w,
                                             float* __restrict__ alpha_g) {
  __shared__ float cw[TR];
  __shared__ float red[48];
  const int b = blockIdx.x, tid = threadIdx.x;
  const int wave = tid >> 6, lane = tid & 63;
  for (int k = tid; k < TR; k += 256) cw[k] = (k < H_) ? conv_w[k] : 0.f;
  __syncthreads();

  const half4* s0 = (const half4*)(hs + (size_t)b * SB2);
  const half4* s1 = (const half4*)(hs + (size_t)(B_ + b) * SB2);
  for (int t = wave; t < T_; t += 4) {
    const int base = t * (TR / 4);
    float p = 0.f;
    {
      half4 a = s0[base + lane], cc = s1[base + lane];
#pragma unroll
      for (int r = 0; r < 4; r++)
        p += tanh_fast((float)a[r] + (float)cc[r]) * cw[lane * 4 + r];
    }
    if (lane < 12) {
      half4 a = s0[base + 64 + lane], cc = s1[base + 64 + lane];
#pragma unroll
      for (int r = 0; r < 4; r++)
        p += tanh_fast((float)a[r] + (float)cc[r]) * cw[256 + lane * 4 + r];
    }
#pragma unroll
    for (int o = 32; o; o >>= 1) p += __shfl_down(p, o);
    if (lane == 0) red[t] = p;
  }
  __syncthreads();
  if (tid < 64) {
    float a = (tid < T_) ? red[tid] : -1e30f;
    float mx = a;
#pragma unroll
    for (int o = 32; o; o >>= 1) mx = fmaxf(mx, __shfl_xor(mx, o));
    float e = (tid < T_) ? __expf(a - mx) : 0.f;
    float s = e;
#pragma unroll
    for (int o = 32; o; o >>= 1) s += __shfl_xor(s, o);
    if (tid < T_) alpha_g[(size_t)b * 44 + tid] = e / s;
  }
}

// ---------------------------------------------------------------------------
// attn2: r[b][h] = sum_t hsum*alpha; hstar = tanh(r); logits; softmax.
// Thread-per-h accumulation, coalesced streaming.
// ---------------------------------------------------------------------------
__global__ __launch_bounds__(256) void attn2(const f16* __restrict__ hs,
                                             const float* __restrict__ alpha_g,
                                             const float* __restrict__ fc_w,
                                             const float* __restrict__ fc_b,
                                             float* __restrict__ out) {
  __shared__ float al[T_];
  __shared__ float hstar[TR];
  __shared__ float lg[NC_];
  const int b = blockIdx.x, tid = threadIdx.x;
  if (tid < T_) al[tid] = alpha_g[(size_t)b * 44 + tid];
  __syncthreads();

  const f16* s0 = hs + (size_t)b * SB2;
  const f16* s1 = hs + (size_t)(B_ + b) * SB2;
  float r0 = 0.f, r1 = 0.f;
  for (int t = 0; t < T_; t++) {
    const float a = al[t];
    r0 += ((float)s0[t * TR + tid] + (float)s1[t * TR + tid]) * a;
    if (tid < 48)
      r1 += ((float)s0[t * TR + 256 + tid] + (float)s1[t * TR + 256 + tid]) * a;
  }
  hstar[tid] = tanh_fast(r0);
  if (tid < 48) hstar[256 + tid] = tanh_fast(r1);
  __syncthreads();

  const int wave = tid >> 6, lane = tid & 63;
  for (int cls = wave; cls < NC_; cls += 4) {
    float p = 0.f;
    for (int k = lane; k < H_; k += 64) p += hstar[k] * fc_w[(size_t)cls * H_ + k];
#pragma unroll
    for (int o = 32; o; o >>= 1) p += __shfl_down(p, o);
    if (lane == 0) lg[cls] = p + fc_b[cls];
  }
  __syncthreads();
  if (tid < 64) {
    float a0 = (tid < 40) ? lg[tid] : -1e30f;
    float a1 = (tid < 40) ? lg[tid + 40] : -1e30f;
    float mx = fmaxf(a0, a1);
#pragma unroll
    for (int o = 32; o; o >>= 1) mx = fmaxf(mx, __shfl_xor(mx, o));
    float e0 = (tid < 40) ? __expf(a0 - mx) : 0.f;
    float e1 = (tid < 40) ? __expf(a1 - mx) : 0.f;
    float s = e0 + e1;
#pragma unroll
    for (int o = 32; o; o >>= 1) s += __shfl_xor(s, o);
    if (tid < 40) {
      out[(size_t)b * NC_ + tid] = e0 / s;
      out[(size_t)b * NC_ + tid + 40] = e1 / s;
    }
  }
}

// ---------------------------------------------------------------------------
extern "C" void kernel_launch(void* const* d_in, const int* in_sizes, int n_in,
                              void* d_out, int out_size, void* d_ws, size_t ws_size,
                              hipStream_t stream) {
  const float* x      = (const float*)d_in[0];
  const float* w_ih   = (const float*)d_in[1];
  const float* w_hh   = (const float*)d_in[2];
  const float* b_ih   = (const float*)d_in[3];
  const float* b_hh   = (const float*)d_in[4];
  const float* conv_w = (const float*)d_in[5];
  const float* fc_w   = (const float*)d_in[6];
  const float* fc_b   = (const float*)d_in[7];
  float* out = (float*)d_out;

  // Workspace carve (~331 MB)
  char* p = (char*)d_ws;
  f16* Wcat = (f16*)p;  p += (size_t)NDD * KC * sizeof(f16);        // 3.3 MB
  float* bias = (float*)p; p += (size_t)NDD * sizeof(float);
  p = (char*)(((uintptr_t)p + 255) & ~(uintptr_t)255);
  f16* xT = (f16*)p;    p += (size_t)T_ * B_ * HP * sizeof(f16);    // 112.7 MB
  f16* hs = (f16*)p;    p += (size_t)2 * B_ * SB2 * sizeof(f16);    // 214.2 MB
  float* alpha_g = (float*)p; p += (size_t)B_ * 44 * sizeof(float); // 0.72 MB

  prep_weights<<<(NDD * KC + 255) / 256, 256, 0, stream>>>(
      w_ih, w_hh, b_ih, b_hh, Wcat, bias);
  prep_xT<<<dim3(B_, 5), 256, 0, stream>>>(x, xT);

  lstm_all<<<dim3(NBT, 2), 256, LDS_TOTAL, stream>>>(xT, Wcat, bias, hs);

  attn1<<<B_, 256, 0, stream>>>(hs, conv_w, alpha_g);
  attn2<<<B_, 256, 0, stream>>>(hs, alpha_g, fc_w, fc_b, out);
}